// Round 3
// baseline (2053.075 us; speedup 1.0000x reference)
//
#include <hip/hip_runtime.h>

#define NN 100000
#define CC 256
#define EE 3200000

__device__ __forceinline__ float4 f4add(float4 a, float4 b) {
  return make_float4(a.x + b.x, a.y + b.y, a.z + b.z, a.w + b.w);
}

// ---- degree histogram (incoming edges; +1 self-loop added analytically later) ----
__global__ void k_deg(const int* __restrict__ dst, int* __restrict__ cnt, int n) {
  int i = blockIdx.x * blockDim.x + threadIdx.x;
  int stride = gridDim.x * blockDim.x;
  for (; i < n; i += stride) {
    unsigned d = (unsigned)dst[i];
    if (d < NN) atomicAdd(&cnt[d], 1);
  }
}

__global__ void k_dis(const int* __restrict__ cnt, float* __restrict__ dis, int n) {
  int i = blockIdx.x * blockDim.x + threadIdx.x;
  if (i < n) dis[i] = 1.0f / sqrtf((float)(cnt[i] + 1));
}

// ---- exclusive scan over cnt -> offs (single block, 1024 threads) ----
__global__ void k_scan(const int* __restrict__ cnt, int* __restrict__ offs, int n) {
  __shared__ int wsum[16];
  __shared__ int carry_s;
  int t = threadIdx.x;
  int lane = t & 63, wv = t >> 6;
  if (t == 0) carry_s = 0;
  __syncthreads();
  for (int base = 0; base < n; base += 1024) {
    int idx = base + t;
    int v = (idx < n) ? cnt[idx] : 0;
    int x = v;
#pragma unroll
    for (int d = 1; d < 64; d <<= 1) {
      int y = __shfl_up(x, d, 64);
      if (lane >= d) x += y;
    }
    if (lane == 63) wsum[wv] = x;
    __syncthreads();
    int wpre = 0, total = 0;
#pragma unroll
    for (int w = 0; w < 16; ++w) {
      int s = wsum[w];
      if (w < wv) wpre += s;
      total += s;
    }
    int carry = carry_s;
    if (idx < n) offs[idx] = carry + wpre + x - v;
    __syncthreads();
    if (t == 0) carry_s = carry + total;
    __syncthreads();
  }
  if (t == 0) offs[n] = carry_s;
}

// ---- scatter edge src indices into CSR slots ----
__global__ void k_scatter(const int* __restrict__ src, const int* __restrict__ dst,
                          const int* __restrict__ offs, int* __restrict__ fill,
                          int* __restrict__ csr, int n) {
  int i = blockIdx.x * blockDim.x + threadIdx.x;
  int stride = gridDim.x * blockDim.x;
  for (; i < n; i += stride) {
    unsigned d = (unsigned)dst[i];
    unsigned s = (unsigned)src[i];
    if (d < NN && s < NN) {
      int p = offs[d] + atomicAdd(&fill[d], 1);
      csr[p] = (int)s;
    }
  }
}

// ---- sort each node's src list ascending: resident waves then sweep the src
// space in loose lockstep, shrinking the instantaneous gather working set so
// it fits aggregate L2 (32 MB) instead of spanning all of hs (102 MB). ----
__global__ void k_sortseg(const int* __restrict__ offs, int* __restrict__ csr, int n) {
  int node = blockIdx.x * blockDim.x + threadIdx.x;
  if (node >= n) return;
  int beg = offs[node], end = offs[node + 1];
  int len = end - beg;
  if (len <= 1) return;
  if (len <= 96) {  // Poisson(32): P(len>96) ~ 0
    int buf[96];
    for (int i = 0; i < len; ++i) buf[i] = csr[beg + i];
    for (int i = 1; i < len; ++i) {
      int key = buf[i];
      int j = i - 1;
      while (j >= 0 && buf[j] > key) { buf[j + 1] = buf[j]; --j; }
      buf[j + 1] = key;
    }
    for (int i = 0; i < len; ++i) csr[beg + i] = buf[i];
  } else {
    for (int i = beg + 1; i < end; ++i) {
      int key = csr[i];
      int j = i - 1;
      while (j >= beg && csr[j] > key) { csr[j + 1] = csr[j]; --j; }
      csr[j + 1] = key;
    }
  }
}

// ---- fp32 GEMM: Out[m][c] = dis[m] * sum_k A[m][k] * W[k][c] ----
#define TM 128
#define TN 128
#define KB 16
#define AS_LD 132

__global__ __launch_bounds__(256) void k_gemm_scale(
    const float* __restrict__ A, const float* __restrict__ W,
    const float* __restrict__ dis, float* __restrict__ Out, int M) {
  __shared__ float As[KB * AS_LD];  // [k][m]
  __shared__ float Bs[KB * TN];     // [k][c]
  const int tid = threadIdx.x;
  const int tx = tid & 15, ty = tid >> 4;
  const int row0 = blockIdx.x * TM;
  const int col0 = blockIdx.y * TN;
  float acc[8][8] = {};

  for (int k0 = 0; k0 < CC; k0 += KB) {
#pragma unroll
    for (int l = tid; l < TM * KB / 4; l += 256) {
      int r = l >> 2;
      int kq = (l & 3) << 2;
      int grow = row0 + r;
      float4 v = make_float4(0.f, 0.f, 0.f, 0.f);
      if (grow < M) v = *(const float4*)&A[(size_t)grow * CC + k0 + kq];
      As[(kq + 0) * AS_LD + r] = v.x;
      As[(kq + 1) * AS_LD + r] = v.y;
      As[(kq + 2) * AS_LD + r] = v.z;
      As[(kq + 3) * AS_LD + r] = v.w;
    }
#pragma unroll
    for (int l = tid; l < KB * TN / 4; l += 256) {
      int kk = l >> 5;
      int cq = (l & 31) << 2;
      *(float4*)&Bs[kk * TN + cq] =
          *(const float4*)&W[(size_t)(k0 + kk) * CC + col0 + cq];
    }
    __syncthreads();
#pragma unroll
    for (int k = 0; k < KB; ++k) {
      float4 a0 = *(const float4*)&As[k * AS_LD + ty * 4];
      float4 a1 = *(const float4*)&As[k * AS_LD + 64 + ty * 4];
      float4 b0 = *(const float4*)&Bs[k * TN + tx * 4];
      float4 b1 = *(const float4*)&Bs[k * TN + 64 + tx * 4];
      float a[8] = {a0.x, a0.y, a0.z, a0.w, a1.x, a1.y, a1.z, a1.w};
      float b[8] = {b0.x, b0.y, b0.z, b0.w, b1.x, b1.y, b1.z, b1.w};
#pragma unroll
      for (int i = 0; i < 8; ++i)
#pragma unroll
        for (int j = 0; j < 8; ++j)
          acc[i][j] += a[i] * b[j];
    }
    __syncthreads();
  }

#pragma unroll
  for (int i = 0; i < 8; ++i) {
    int r = row0 + (i < 4 ? ty * 4 + i : 64 + ty * 4 + (i - 4));
    if (r < M) {
      float sc = dis[r];
      float4 v0 = make_float4(acc[i][0] * sc, acc[i][1] * sc, acc[i][2] * sc, acc[i][3] * sc);
      float4 v1 = make_float4(acc[i][4] * sc, acc[i][5] * sc, acc[i][6] * sc, acc[i][7] * sc);
      float* o = &Out[(size_t)r * CC + col0 + tx * 4];
      *(float4*)o = v0;
      *(float4*)(o + 64) = v1;
    }
  }
}

// ---- CSR aggregation: out[i] = relu(dis[i]*(sum_{e in(i)} hs[src_e] + hs[i]) + b) ----
__global__ __launch_bounds__(256) void k_aggregate(
    const float* __restrict__ hs, const int* __restrict__ offs,
    const int* __restrict__ csr, const float* __restrict__ dis,
    const float* __restrict__ bias, float* __restrict__ out, int n) {
  int node = blockIdx.x * 4 + (threadIdx.x >> 6);
  if (node >= n) return;
  int lane = threadIdx.x & 63;
  int c4 = lane << 2;
  int beg = offs[node], end = offs[node + 1];
  float4 a0 = *(const float4*)&hs[(size_t)node * CC + c4];  // self-loop term
  float4 a1 = make_float4(0.f, 0.f, 0.f, 0.f);
  float4 a2 = make_float4(0.f, 0.f, 0.f, 0.f);
  float4 a3 = make_float4(0.f, 0.f, 0.f, 0.f);
  int e = beg;
  for (; e + 4 <= end; e += 4) {
    int s0 = csr[e], s1 = csr[e + 1], s2 = csr[e + 2], s3 = csr[e + 3];
    float4 v0 = *(const float4*)&hs[(size_t)s0 * CC + c4];
    float4 v1 = *(const float4*)&hs[(size_t)s1 * CC + c4];
    float4 v2 = *(const float4*)&hs[(size_t)s2 * CC + c4];
    float4 v3 = *(const float4*)&hs[(size_t)s3 * CC + c4];
    a0 = f4add(a0, v0);
    a1 = f4add(a1, v1);
    a2 = f4add(a2, v2);
    a3 = f4add(a3, v3);
  }
  for (; e < end; ++e) {
    int s0 = csr[e];
    a0 = f4add(a0, *(const float4*)&hs[(size_t)s0 * CC + c4]);
  }
  float4 acc = f4add(f4add(a0, a1), f4add(a2, a3));
  float sc = dis[node];
  float4 bv = *(const float4*)&bias[c4];
  float4 r;
  r.x = fmaxf(acc.x * sc + bv.x, 0.f);
  r.y = fmaxf(acc.y * sc + bv.y, 0.f);
  r.z = fmaxf(acc.z * sc + bv.z, 0.f);
  r.w = fmaxf(acc.w * sc + bv.w, 0.f);
  *(float4*)&out[(size_t)node * CC + c4] = r;
}

// ---- final projection: out[i] = h2[i] . Wl + bl ----
__global__ __launch_bounds__(256) void k_final(
    const float* __restrict__ h, const float* __restrict__ Wl,
    const float* __restrict__ bl, float* __restrict__ out, int n) {
  int node = blockIdx.x * 4 + (threadIdx.x >> 6);
  if (node >= n) return;
  int lane = threadIdx.x & 63;
  float4 a = *(const float4*)&h[(size_t)node * CC + (lane << 2)];
  float4 w = *(const float4*)&Wl[lane << 2];
  float s = a.x * w.x + a.y * w.y + a.z * w.z + a.w * w.w;
#pragma unroll
  for (int d = 32; d > 0; d >>= 1) s += __shfl_down(s, d, 64);
  if (lane == 0) out[node] = s + bl[0];
}

extern "C" void kernel_launch(void* const* d_in, const int* in_sizes, int n_in,
                              void* d_out, int out_size, void* d_ws, size_t ws_size,
                              hipStream_t stream) {
  const float* x = (const float*)d_in[0];
  const int* ei = (const int*)d_in[1];  // harness delivers integer inputs as int32
  const float* W1 = (const float*)d_in[2];
  const float* b1 = (const float*)d_in[3];
  const float* W2 = (const float*)d_in[4];
  const float* b2 = (const float*)d_in[5];
  const float* Wl = (const float*)d_in[6];
  const float* bl = (const float*)d_in[7];
  float* out = (float*)d_out;

  const int* src = ei;
  const int* dst = ei + EE;

  char* ws = (char*)d_ws;
  size_t off = 0;
  auto alloc = [&](size_t bytes) {
    char* p = ws + off;
    off = (off + bytes + 255) & ~(size_t)255;
    return p;
  };
  float* dis = (float*)alloc((size_t)NN * 4);
  int* cnt = (int*)alloc((size_t)NN * 4);   // reused as `fill` during scatter
  int* offs = (int*)alloc((size_t)(NN + 1) * 4);
  int* csr = (int*)alloc((size_t)EE * 4);
  float* bufA = (float*)alloc((size_t)NN * CC * 4);  // hs (scaled GEMM out)
  float* bufB = (float*)alloc((size_t)NN * CC * 4);  // h1 / h2

  hipMemsetAsync(cnt, 0, (size_t)NN * 4, stream);

  k_deg<<<2048, 256, 0, stream>>>(dst, cnt, EE);
  k_dis<<<(NN + 255) / 256, 256, 0, stream>>>(cnt, dis, NN);
  k_scan<<<1, 1024, 0, stream>>>(cnt, offs, NN);
  // cnt is dead now -> reuse as fill counters
  hipMemsetAsync(cnt, 0, (size_t)NN * 4, stream);
  k_scatter<<<2048, 256, 0, stream>>>(src, dst, offs, cnt, csr, EE);
  k_sortseg<<<(NN + 255) / 256, 256, 0, stream>>>(offs, csr, NN);

  dim3 ggrid((NN + TM - 1) / TM, CC / TN);
  // layer 1: hs = (x @ W1) * dis[row]; h1 = relu(dis*(agg+self) + b1)
  k_gemm_scale<<<ggrid, 256, 0, stream>>>(x, W1, dis, bufA, NN);
  k_aggregate<<<(NN + 3) / 4, 256, 0, stream>>>(bufA, offs, csr, dis, b1, bufB, NN);
  // layer 2
  k_gemm_scale<<<ggrid, 256, 0, stream>>>(bufB, W2, dis, bufA, NN);
  k_aggregate<<<(NN + 3) / 4, 256, 0, stream>>>(bufA, offs, csr, dis, b2, bufB, NN);
  // readout
  k_final<<<(NN + 3) / 4, 256, 0, stream>>>(bufB, Wl, bl, out, NN);
}

// Round 4
// 1588.026 us; speedup vs baseline: 1.2928x; 1.2928x over previous
//
#include <hip/hip_runtime.h>

#define NN 100000
#define CC 256
#define EE 3200000

typedef __attribute__((ext_vector_type(8))) short bf16x8;
typedef __attribute__((ext_vector_type(4))) float f32x4;

__device__ __forceinline__ float4 f4add(float4 a, float4 b) {
  return make_float4(a.x + b.x, a.y + b.y, a.z + b.z, a.w + b.w);
}

__device__ __forceinline__ unsigned short f2bf(float f) {
  unsigned u = __float_as_uint(f);
  unsigned r = (u + 0x7fffu + ((u >> 16) & 1u)) >> 16;  // RTNE
  return (unsigned short)r;
}
__device__ __forceinline__ float bf2f(unsigned short h) {
  return __uint_as_float(((unsigned)h) << 16);
}

// ---- degree histogram ----
__global__ void k_deg(const int* __restrict__ dst, int* __restrict__ cnt, int n) {
  int i = blockIdx.x * blockDim.x + threadIdx.x;
  int stride = gridDim.x * blockDim.x;
  for (; i < n; i += stride) {
    unsigned d = (unsigned)dst[i];
    if (d < NN) atomicAdd(&cnt[d], 1);
  }
}

__global__ void k_dis(const int* __restrict__ cnt, float* __restrict__ dis, int n) {
  int i = blockIdx.x * blockDim.x + threadIdx.x;
  if (i < n) dis[i] = 1.0f / sqrtf((float)(cnt[i] + 1));
}

// ---- 3-phase parallel exclusive scan ----
__global__ void k_scan_local(const int* __restrict__ cnt, int* __restrict__ offs,
                             int* __restrict__ bsum, int n) {
  __shared__ int wsum[16];
  int t = threadIdx.x;
  int idx = blockIdx.x * 1024 + t;
  int lane = t & 63, wv = t >> 6;
  int v = (idx < n) ? cnt[idx] : 0;
  int x = v;
#pragma unroll
  for (int d = 1; d < 64; d <<= 1) {
    int y = __shfl_up(x, d, 64);
    if (lane >= d) x += y;
  }
  if (lane == 63) wsum[wv] = x;
  __syncthreads();
  int wpre = 0, total = 0;
#pragma unroll
  for (int w = 0; w < 16; ++w) {
    int s = wsum[w];
    if (w < wv) wpre += s;
    total += s;
  }
  if (idx < n) offs[idx] = wpre + x - v;
  if (t == 0) bsum[blockIdx.x] = total;
}

__global__ void k_scan_bsum(const int* __restrict__ bsum, int* __restrict__ bbase, int nb) {
  __shared__ int wsum[2];
  int t = threadIdx.x;  // 128 threads, nb <= 128
  int lane = t & 63, wv = t >> 6;
  int v = (t < nb) ? bsum[t] : 0;
  int x = v;
#pragma unroll
  for (int d = 1; d < 64; d <<= 1) {
    int y = __shfl_up(x, d, 64);
    if (lane >= d) x += y;
  }
  if (lane == 63) wsum[wv] = x;
  __syncthreads();
  int pre = (wv == 1) ? wsum[0] : 0;
  if (t <= nb) {
    // exclusive base for block t; also write grand total at [nb]
    if (t < nb) bbase[t] = pre + x - v;
  }
  if (t == nb - 1) bbase[nb] = pre + x;  // grand total
}

__global__ void k_scan_add(int* __restrict__ offs, const int* __restrict__ bbase,
                           int n, int nb) {
  int i = blockIdx.x * 256 + threadIdx.x;
  if (i < n) offs[i] += bbase[i >> 10];
  if (i == 0) offs[n] = bbase[nb];
}

// ---- scatter edge src indices into CSR slots ----
__global__ void k_scatter(const int* __restrict__ src, const int* __restrict__ dst,
                          const int* __restrict__ offs, int* __restrict__ fill,
                          int* __restrict__ csr, int n) {
  int i = blockIdx.x * blockDim.x + threadIdx.x;
  int stride = gridDim.x * blockDim.x;
  for (; i < n; i += stride) {
    unsigned d = (unsigned)dst[i];
    unsigned s = (unsigned)src[i];
    if (d < NN && s < NN) {
      int p = offs[d] + atomicAdd(&fill[d], 1);
      csr[p] = (int)s;
    }
  }
}

// ---- split W[k][n] (fp32) into transposed bf16 hi/lo: WT[n][k] ----
__global__ void k_wsplit(const float* __restrict__ W, unsigned short* __restrict__ WTh,
                         unsigned short* __restrict__ WTl) {
  int k = blockIdx.x, n = threadIdx.x;
  float w = W[k * CC + n];
  unsigned short h = f2bf(w);
  unsigned short l = f2bf(w - bf2f(h));
  WTh[n * CC + k] = h;
  WTl[n * CC + k] = l;
}

// ---- split-bf16 MFMA GEMM: Out[m][n] = dis[m] * sum_k A[m][k]*W[k][n] ----
// A split on the fly into hi+lo bf16; W pre-split/transposed.
// A*W ~= Ah*Wh + Al*Wh + Ah*Wl  (lo*lo term ~2^-18 rel, dropped)
#define LDA 40  // bf16 row stride: 80 B, 16B-aligned, breaks pow2 bank stride

__global__ __launch_bounds__(256) void k_gemm_mfma(
    const float* __restrict__ A, const unsigned short* __restrict__ WTh,
    const unsigned short* __restrict__ WTl, const float* __restrict__ dis,
    float* __restrict__ Out, int M) {
  __shared__ unsigned short Ah[128 * LDA], Al[128 * LDA];
  __shared__ unsigned short Bh[128 * LDA], Bl[128 * LDA];
  const int tid = threadIdx.x;
  const int wave = tid >> 6, lane = tid & 63;
  const int quad = lane >> 4, l16 = lane & 15;
  const int wm = wave >> 1, wn = wave & 1;  // 2x2 wave grid, 64x64 each
  const int row0 = blockIdx.x * 128;
  const int n0 = blockIdx.y * 128;

  f32x4 acc[4][4];
#pragma unroll
  for (int i = 0; i < 4; ++i)
#pragma unroll
    for (int j = 0; j < 4; ++j) acc[i][j] = (f32x4){0.f, 0.f, 0.f, 0.f};

  for (int k0 = 0; k0 < CC; k0 += 32) {
    // stage A tile (128 x 32 fp32 -> bf16 hi/lo), 4 float4 per thread
#pragma unroll
    for (int q = 0; q < 4; ++q) {
      int idx = tid + 256 * q;
      int r = idx >> 3;
      int c4 = (idx & 7) << 2;
      int gr = row0 + r;
      float4 v = make_float4(0.f, 0.f, 0.f, 0.f);
      if (gr < M) v = *(const float4*)&A[(size_t)gr * CC + k0 + c4];
      ushort4 hv, lv;
      hv.x = f2bf(v.x); lv.x = f2bf(v.x - bf2f(hv.x));
      hv.y = f2bf(v.y); lv.y = f2bf(v.y - bf2f(hv.y));
      hv.z = f2bf(v.z); lv.z = f2bf(v.z - bf2f(hv.z));
      hv.w = f2bf(v.w); lv.w = f2bf(v.w - bf2f(hv.w));
      *(ushort4*)&Ah[r * LDA + c4] = hv;
      *(ushort4*)&Al[r * LDA + c4] = lv;
    }
    // stage B tile (128 n-rows x 32 k, already bf16, transposed layout)
#pragma unroll
    for (int q = 0; q < 4; ++q) {
      int idx = tid + 256 * q;
      int r = idx >> 3;
      int c4 = (idx & 7) << 2;
      const size_t g = (size_t)(n0 + r) * CC + k0 + c4;
      *(ushort4*)&Bh[r * LDA + c4] = *(const ushort4*)&WTh[g];
      *(ushort4*)&Bl[r * LDA + c4] = *(const ushort4*)&WTl[g];
    }
    __syncthreads();

    bf16x8 bh[4], bl[4];
#pragma unroll
    for (int j = 0; j < 4; ++j) {
      int br = (wn * 64 + j * 16 + l16) * LDA + quad * 8;
      bh[j] = *(const bf16x8*)&Bh[br];
      bl[j] = *(const bf16x8*)&Bl[br];
    }
#pragma unroll
    for (int i = 0; i < 4; ++i) {
      int ar = (wm * 64 + i * 16 + l16) * LDA + quad * 8;
      bf16x8 ah = *(const bf16x8*)&Ah[ar];
      bf16x8 al = *(const bf16x8*)&Al[ar];
#pragma unroll
      for (int j = 0; j < 4; ++j) {
        acc[i][j] = __builtin_amdgcn_mfma_f32_16x16x32_bf16(ah, bh[j], acc[i][j], 0, 0, 0);
        acc[i][j] = __builtin_amdgcn_mfma_f32_16x16x32_bf16(al, bh[j], acc[i][j], 0, 0, 0);
        acc[i][j] = __builtin_amdgcn_mfma_f32_16x16x32_bf16(ah, bl[j], acc[i][j], 0, 0, 0);
      }
    }
    __syncthreads();
  }

  // epilogue: D layout col=lane&15, row=quad*4+reg (m89-verified)
#pragma unroll
  for (int i = 0; i < 4; ++i) {
#pragma unroll
    for (int r4 = 0; r4 < 4; ++r4) {
      int r = row0 + wm * 64 + i * 16 + quad * 4 + r4;
      if (r < M) {
        float sc = dis[r];
#pragma unroll
        for (int j = 0; j < 4; ++j) {
          Out[(size_t)r * CC + n0 + wn * 64 + j * 16 + l16] = acc[i][j][r4] * sc;
        }
      }
    }
  }
}

// ---- CSR aggregation: out[i] = relu(dis[i]*(sum_{e in(i)} hs[src_e] + hs[i]) + b) ----
__global__ __launch_bounds__(256) void k_aggregate(
    const float* __restrict__ hs, const int* __restrict__ offs,
    const int* __restrict__ csr, const float* __restrict__ dis,
    const float* __restrict__ bias, float* __restrict__ out, int n) {
  int node = blockIdx.x * 4 + (threadIdx.x >> 6);
  if (node >= n) return;
  int lane = threadIdx.x & 63;
  int c4 = lane << 2;
  int beg = offs[node], end = offs[node + 1];
  float4 a0 = *(const float4*)&hs[(size_t)node * CC + c4];  // self-loop term
  float4 a1 = make_float4(0.f, 0.f, 0.f, 0.f);
  int e = beg;
  for (; e + 2 <= end; e += 2) {
    int s0 = csr[e], s1 = csr[e + 1];
    float4 v0 = *(const float4*)&hs[(size_t)s0 * CC + c4];
    float4 v1 = *(const float4*)&hs[(size_t)s1 * CC + c4];
    a0 = f4add(a0, v0);
    a1 = f4add(a1, v1);
  }
  if (e < end) {
    int s0 = csr[e];
    a0 = f4add(a0, *(const float4*)&hs[(size_t)s0 * CC + c4]);
  }
  float4 acc = f4add(a0, a1);
  float sc = dis[node];
  float4 bv = *(const float4*)&bias[c4];
  float4 r;
  r.x = fmaxf(acc.x * sc + bv.x, 0.f);
  r.y = fmaxf(acc.y * sc + bv.y, 0.f);
  r.z = fmaxf(acc.z * sc + bv.z, 0.f);
  r.w = fmaxf(acc.w * sc + bv.w, 0.f);
  *(float4*)&out[(size_t)node * CC + c4] = r;
}

// ---- final projection: out[i] = h2[i] . Wl + bl ----
__global__ __launch_bounds__(256) void k_final(
    const float* __restrict__ h, const float* __restrict__ Wl,
    const float* __restrict__ bl, float* __restrict__ out, int n) {
  int node = blockIdx.x * 4 + (threadIdx.x >> 6);
  if (node >= n) return;
  int lane = threadIdx.x & 63;
  float4 a = *(const float4*)&h[(size_t)node * CC + (lane << 2)];
  float4 w = *(const float4*)&Wl[lane << 2];
  float s = a.x * w.x + a.y * w.y + a.z * w.z + a.w * w.w;
#pragma unroll
  for (int d = 32; d > 0; d >>= 1) s += __shfl_down(s, d, 64);
  if (lane == 0) out[node] = s + bl[0];
}

extern "C" void kernel_launch(void* const* d_in, const int* in_sizes, int n_in,
                              void* d_out, int out_size, void* d_ws, size_t ws_size,
                              hipStream_t stream) {
  const float* x = (const float*)d_in[0];
  const int* ei = (const int*)d_in[1];  // int64 in reference -> int32 on device
  const float* W1 = (const float*)d_in[2];
  const float* b1 = (const float*)d_in[3];
  const float* W2 = (const float*)d_in[4];
  const float* b2 = (const float*)d_in[5];
  const float* Wl = (const float*)d_in[6];
  const float* bl = (const float*)d_in[7];
  float* out = (float*)d_out;

  const int* src = ei;
  const int* dst = ei + EE;

  char* ws = (char*)d_ws;
  size_t off = 0;
  auto alloc = [&](size_t bytes) {
    char* p = ws + off;
    off = (off + bytes + 255) & ~(size_t)255;
    return p;
  };
  float* dis = (float*)alloc((size_t)NN * 4);
  int* cnt = (int*)alloc((size_t)NN * 4);   // reused as `fill` during scatter
  int* offs = (int*)alloc((size_t)(NN + 1) * 4);
  int* scanb = (int*)alloc(1024 * 4);       // bsum
  int* scanb2 = (int*)alloc(1024 * 4);      // bbase
  int* csr = (int*)alloc((size_t)EE * 4);
  unsigned short* W1h = (unsigned short*)alloc((size_t)CC * CC * 2);
  unsigned short* W1l = (unsigned short*)alloc((size_t)CC * CC * 2);
  unsigned short* W2h = (unsigned short*)alloc((size_t)CC * CC * 2);
  unsigned short* W2l = (unsigned short*)alloc((size_t)CC * CC * 2);
  float* bufA = (float*)alloc((size_t)NN * CC * 4);  // hs (scaled GEMM out)
  float* bufB = (float*)alloc((size_t)NN * CC * 4);  // h1 / h2

  hipMemsetAsync(cnt, 0, (size_t)NN * 4, stream);

  k_deg<<<2048, 256, 0, stream>>>(dst, cnt, EE);
  k_dis<<<(NN + 255) / 256, 256, 0, stream>>>(cnt, dis, NN);
  const int nb = (NN + 1023) / 1024;  // 98
  k_scan_local<<<nb, 1024, 0, stream>>>(cnt, offs, scanb, NN);
  k_scan_bsum<<<1, 128, 0, stream>>>(scanb, scanb2, nb);
  k_scan_add<<<(NN + 255) / 256, 256, 0, stream>>>(offs, scanb2, NN, nb);
  // cnt dead -> reuse as fill counters
  hipMemsetAsync(cnt, 0, (size_t)NN * 4, stream);
  k_scatter<<<2048, 256, 0, stream>>>(src, dst, offs, cnt, csr, EE);

  // weight prep (once per launch, ~128 KB each)
  k_wsplit<<<CC, CC, 0, stream>>>(W1, W1h, W1l);
  k_wsplit<<<CC, CC, 0, stream>>>(W2, W2h, W2l);

  dim3 ggrid((NN + 127) / 128, CC / 128);
  // layer 1: hs = (x @ W1) * dis[row]; h1 = relu(dis*(agg+self) + b1)
  k_gemm_mfma<<<ggrid, 256, 0, stream>>>(x, W1h, W1l, dis, bufA, NN);
  k_aggregate<<<(NN + 3) / 4, 256, 0, stream>>>(bufA, offs, csr, dis, b1, bufB, NN);
  // layer 2
  k_gemm_mfma<<<ggrid, 256, 0, stream>>>(bufB, W2h, W2l, dis, bufA, NN);
  k_aggregate<<<(NN + 3) / 4, 256, 0, stream>>>(bufA, offs, csr, dis, b2, bufB, NN);
  // readout
  k_final<<<(NN + 3) / 4, 256, 0, stream>>>(bufB, Wl, bl, out, NN);
}

// Round 5
// 1106.462 us; speedup vs baseline: 1.8555x; 1.4352x over previous
//
#include <hip/hip_runtime.h>

#define NN 100000
#define CC 256
#define EE 3200000

typedef __attribute__((ext_vector_type(8))) short bf16x8;
typedef __attribute__((ext_vector_type(4))) float f32x4;
typedef __attribute__((ext_vector_type(4))) _Float16 f16x4;

__device__ __forceinline__ float4 f4add(float4 a, float4 b) {
  return make_float4(a.x + b.x, a.y + b.y, a.z + b.z, a.w + b.w);
}

__device__ __forceinline__ unsigned short f2bf(float f) {
  unsigned u = __float_as_uint(f);
  unsigned r = (u + 0x7fffu + ((u >> 16) & 1u)) >> 16;  // RTNE
  return (unsigned short)r;
}
__device__ __forceinline__ float bf2f(unsigned short h) {
  return __uint_as_float(((unsigned)h) << 16);
}

// ---- degree histogram ----
__global__ void k_deg(const int* __restrict__ dst, int* __restrict__ cnt, int n) {
  int i = blockIdx.x * blockDim.x + threadIdx.x;
  int stride = gridDim.x * blockDim.x;
  for (; i < n; i += stride) {
    unsigned d = (unsigned)dst[i];
    if (d < NN) atomicAdd(&cnt[d], 1);
  }
}

__global__ void k_dis(const int* __restrict__ cnt, float* __restrict__ dis, int n) {
  int i = blockIdx.x * blockDim.x + threadIdx.x;
  if (i < n) dis[i] = 1.0f / sqrtf((float)(cnt[i] + 1));
}

// ---- 3-phase parallel exclusive scan ----
__global__ void k_scan_local(const int* __restrict__ cnt, int* __restrict__ offs,
                             int* __restrict__ bsum, int n) {
  __shared__ int wsum[16];
  int t = threadIdx.x;
  int idx = blockIdx.x * 1024 + t;
  int lane = t & 63, wv = t >> 6;
  int v = (idx < n) ? cnt[idx] : 0;
  int x = v;
#pragma unroll
  for (int d = 1; d < 64; d <<= 1) {
    int y = __shfl_up(x, d, 64);
    if (lane >= d) x += y;
  }
  if (lane == 63) wsum[wv] = x;
  __syncthreads();
  int wpre = 0, total = 0;
#pragma unroll
  for (int w = 0; w < 16; ++w) {
    int s = wsum[w];
    if (w < wv) wpre += s;
    total += s;
  }
  if (idx < n) offs[idx] = wpre + x - v;
  if (t == 0) bsum[blockIdx.x] = total;
}

__global__ void k_scan_bsum(const int* __restrict__ bsum, int* __restrict__ bbase, int nb) {
  __shared__ int wsum[2];
  int t = threadIdx.x;  // 128 threads, nb <= 128
  int lane = t & 63, wv = t >> 6;
  int v = (t < nb) ? bsum[t] : 0;
  int x = v;
#pragma unroll
  for (int d = 1; d < 64; d <<= 1) {
    int y = __shfl_up(x, d, 64);
    if (lane >= d) x += y;
  }
  if (lane == 63) wsum[wv] = x;
  __syncthreads();
  int pre = (wv == 1) ? wsum[0] : 0;
  if (t < nb) bbase[t] = pre + x - v;
  if (t == nb - 1) bbase[nb] = pre + x;  // grand total
}

__global__ void k_scan_add(int* __restrict__ offs, const int* __restrict__ bbase,
                           int n, int nb) {
  int i = blockIdx.x * 256 + threadIdx.x;
  if (i < n) offs[i] += bbase[i >> 10];
  if (i == 0) offs[n] = bbase[nb];
}

// ---- scatter edge src indices into CSR slots ----
__global__ void k_scatter(const int* __restrict__ src, const int* __restrict__ dst,
                          const int* __restrict__ offs, int* __restrict__ fill,
                          int* __restrict__ csr, int n) {
  int i = blockIdx.x * blockDim.x + threadIdx.x;
  int stride = gridDim.x * blockDim.x;
  for (; i < n; i += stride) {
    unsigned d = (unsigned)dst[i];
    unsigned s = (unsigned)src[i];
    if (d < NN && s < NN) {
      int p = offs[d] + atomicAdd(&fill[d], 1);
      csr[p] = (int)s;
    }
  }
}

// ---- split W[k][n] (fp32) into transposed bf16 hi/lo: WT[n][k] ----
__global__ void k_wsplit(const float* __restrict__ W, unsigned short* __restrict__ WTh,
                         unsigned short* __restrict__ WTl) {
  int k = blockIdx.x, n = threadIdx.x;
  float w = W[k * CC + n];
  unsigned short h = f2bf(w);
  unsigned short l = f2bf(w - bf2f(h));
  WTh[n * CC + k] = h;
  WTl[n * CC + k] = l;
}

// ---- split-bf16 MFMA GEMM: Out[m][n] (fp16) = dis[m] * sum_k A[m][k]*W[k][n] ----
// A split on the fly into hi+lo bf16; W pre-split/transposed.
// A*W ~= Ah*Wh + Al*Wh + Ah*Wl  (lo*lo term ~2^-18 rel, dropped)
#define LDA 40  // bf16 row stride: 80 B, 16B-aligned, breaks pow2 bank stride

__global__ __launch_bounds__(256) void k_gemm_mfma(
    const float* __restrict__ A, const unsigned short* __restrict__ WTh,
    const unsigned short* __restrict__ WTl, const float* __restrict__ dis,
    _Float16* __restrict__ Out, int M) {
  __shared__ unsigned short Ah[128 * LDA], Al[128 * LDA];
  __shared__ unsigned short Bh[128 * LDA], Bl[128 * LDA];
  const int tid = threadIdx.x;
  const int wave = tid >> 6, lane = tid & 63;
  const int quad = lane >> 4, l16 = lane & 15;
  const int wm = wave >> 1, wn = wave & 1;  // 2x2 wave grid, 64x64 each
  const int row0 = blockIdx.x * 128;
  const int n0 = blockIdx.y * 128;

  f32x4 acc[4][4];
#pragma unroll
  for (int i = 0; i < 4; ++i)
#pragma unroll
    for (int j = 0; j < 4; ++j) acc[i][j] = (f32x4){0.f, 0.f, 0.f, 0.f};

  for (int k0 = 0; k0 < CC; k0 += 32) {
    // stage A tile (128 x 32 fp32 -> bf16 hi/lo), 4 float4 per thread
#pragma unroll
    for (int q = 0; q < 4; ++q) {
      int idx = tid + 256 * q;
      int r = idx >> 3;
      int c4 = (idx & 7) << 2;
      int gr = row0 + r;
      float4 v = make_float4(0.f, 0.f, 0.f, 0.f);
      if (gr < M) v = *(const float4*)&A[(size_t)gr * CC + k0 + c4];
      ushort4 hv, lv;
      hv.x = f2bf(v.x); lv.x = f2bf(v.x - bf2f(hv.x));
      hv.y = f2bf(v.y); lv.y = f2bf(v.y - bf2f(hv.y));
      hv.z = f2bf(v.z); lv.z = f2bf(v.z - bf2f(hv.z));
      hv.w = f2bf(v.w); lv.w = f2bf(v.w - bf2f(hv.w));
      *(ushort4*)&Ah[r * LDA + c4] = hv;
      *(ushort4*)&Al[r * LDA + c4] = lv;
    }
    // stage B tile (128 n-rows x 32 k, already bf16, transposed layout)
#pragma unroll
    for (int q = 0; q < 4; ++q) {
      int idx = tid + 256 * q;
      int r = idx >> 3;
      int c4 = (idx & 7) << 2;
      const size_t g = (size_t)(n0 + r) * CC + k0 + c4;
      *(ushort4*)&Bh[r * LDA + c4] = *(const ushort4*)&WTh[g];
      *(ushort4*)&Bl[r * LDA + c4] = *(const ushort4*)&WTl[g];
    }
    __syncthreads();

    bf16x8 bh[4], bl[4];
#pragma unroll
    for (int j = 0; j < 4; ++j) {
      int br = (wn * 64 + j * 16 + l16) * LDA + quad * 8;
      bh[j] = *(const bf16x8*)&Bh[br];
      bl[j] = *(const bf16x8*)&Bl[br];
    }
#pragma unroll
    for (int i = 0; i < 4; ++i) {
      int ar = (wm * 64 + i * 16 + l16) * LDA + quad * 8;
      bf16x8 ah = *(const bf16x8*)&Ah[ar];
      bf16x8 al = *(const bf16x8*)&Al[ar];
#pragma unroll
      for (int j = 0; j < 4; ++j) {
        acc[i][j] = __builtin_amdgcn_mfma_f32_16x16x32_bf16(ah, bh[j], acc[i][j], 0, 0, 0);
        acc[i][j] = __builtin_amdgcn_mfma_f32_16x16x32_bf16(al, bh[j], acc[i][j], 0, 0, 0);
        acc[i][j] = __builtin_amdgcn_mfma_f32_16x16x32_bf16(ah, bl[j], acc[i][j], 0, 0, 0);
      }
    }
    __syncthreads();
  }

  // epilogue: D layout col=lane&15, row=quad*4+reg (m89-verified); fp16 store
#pragma unroll
  for (int i = 0; i < 4; ++i) {
#pragma unroll
    for (int r4 = 0; r4 < 4; ++r4) {
      int r = row0 + wm * 64 + i * 16 + quad * 4 + r4;
      if (r < M) {
        float sc = dis[r];
#pragma unroll
        for (int j = 0; j < 4; ++j) {
          Out[(size_t)r * CC + n0 + wn * 64 + j * 16 + l16] =
              (_Float16)(acc[i][j][r4] * sc);
        }
      }
    }
  }
}

// ---- CSR aggregation (fp16 gather): h1[i] = relu(dis[i]*(sum hs[src] + hs[i]) + b) ----
__global__ __launch_bounds__(256) void k_aggregate(
    const _Float16* __restrict__ hs, const int* __restrict__ offs,
    const int* __restrict__ csr, const float* __restrict__ dis,
    const float* __restrict__ bias, float* __restrict__ out, int n) {
  int node = blockIdx.x * 4 + (threadIdx.x >> 6);
  if (node >= n) return;
  int lane = threadIdx.x & 63;
  int c4 = lane << 2;
  int beg = offs[node], end = offs[node + 1];
  f16x4 sv = *(const f16x4*)&hs[(size_t)node * CC + c4];  // self-loop term
  float4 a0 = make_float4((float)sv.x, (float)sv.y, (float)sv.z, (float)sv.w);
  float4 a1 = make_float4(0.f, 0.f, 0.f, 0.f);
  int e = beg;
  for (; e + 2 <= end; e += 2) {
    int s0 = csr[e], s1 = csr[e + 1];
    f16x4 v0 = *(const f16x4*)&hs[(size_t)s0 * CC + c4];
    f16x4 v1 = *(const f16x4*)&hs[(size_t)s1 * CC + c4];
    a0.x += (float)v0.x; a0.y += (float)v0.y; a0.z += (float)v0.z; a0.w += (float)v0.w;
    a1.x += (float)v1.x; a1.y += (float)v1.y; a1.z += (float)v1.z; a1.w += (float)v1.w;
  }
  if (e < end) {
    int s0 = csr[e];
    f16x4 v0 = *(const f16x4*)&hs[(size_t)s0 * CC + c4];
    a0.x += (float)v0.x; a0.y += (float)v0.y; a0.z += (float)v0.z; a0.w += (float)v0.w;
  }
  float4 acc = f4add(a0, a1);
  float sc = dis[node];
  float4 bv = *(const float4*)&bias[c4];
  float4 r;
  r.x = fmaxf(acc.x * sc + bv.x, 0.f);
  r.y = fmaxf(acc.y * sc + bv.y, 0.f);
  r.z = fmaxf(acc.z * sc + bv.z, 0.f);
  r.w = fmaxf(acc.w * sc + bv.w, 0.f);
  *(float4*)&out[(size_t)node * CC + c4] = r;
}

// ---- fused layer-2 aggregate + readout: out[i] = relu(...) . Wl + bl ----
__global__ __launch_bounds__(256) void k_aggregate_final(
    const _Float16* __restrict__ hs, const int* __restrict__ offs,
    const int* __restrict__ csr, const float* __restrict__ dis,
    const float* __restrict__ bias, const float* __restrict__ Wl,
    const float* __restrict__ bl, float* __restrict__ out, int n) {
  int node = blockIdx.x * 4 + (threadIdx.x >> 6);
  if (node >= n) return;
  int lane = threadIdx.x & 63;
  int c4 = lane << 2;
  int beg = offs[node], end = offs[node + 1];
  f16x4 sv = *(const f16x4*)&hs[(size_t)node * CC + c4];
  float4 a0 = make_float4((float)sv.x, (float)sv.y, (float)sv.z, (float)sv.w);
  float4 a1 = make_float4(0.f, 0.f, 0.f, 0.f);
  int e = beg;
  for (; e + 2 <= end; e += 2) {
    int s0 = csr[e], s1 = csr[e + 1];
    f16x4 v0 = *(const f16x4*)&hs[(size_t)s0 * CC + c4];
    f16x4 v1 = *(const f16x4*)&hs[(size_t)s1 * CC + c4];
    a0.x += (float)v0.x; a0.y += (float)v0.y; a0.z += (float)v0.z; a0.w += (float)v0.w;
    a1.x += (float)v1.x; a1.y += (float)v1.y; a1.z += (float)v1.z; a1.w += (float)v1.w;
  }
  if (e < end) {
    int s0 = csr[e];
    f16x4 v0 = *(const f16x4*)&hs[(size_t)s0 * CC + c4];
    a0.x += (float)v0.x; a0.y += (float)v0.y; a0.z += (float)v0.z; a0.w += (float)v0.w;
  }
  float4 acc = f4add(a0, a1);
  float sc = dis[node];
  float4 bv = *(const float4*)&bias[c4];
  float4 w = *(const float4*)&Wl[c4];
  float s = fmaxf(acc.x * sc + bv.x, 0.f) * w.x +
            fmaxf(acc.y * sc + bv.y, 0.f) * w.y +
            fmaxf(acc.z * sc + bv.z, 0.f) * w.z +
            fmaxf(acc.w * sc + bv.w, 0.f) * w.w;
#pragma unroll
  for (int d = 32; d > 0; d >>= 1) s += __shfl_down(s, d, 64);
  if (lane == 0) out[node] = s + bl[0];
}

extern "C" void kernel_launch(void* const* d_in, const int* in_sizes, int n_in,
                              void* d_out, int out_size, void* d_ws, size_t ws_size,
                              hipStream_t stream) {
  const float* x = (const float*)d_in[0];
  const int* ei = (const int*)d_in[1];  // int64 in reference -> int32 on device
  const float* W1 = (const float*)d_in[2];
  const float* b1 = (const float*)d_in[3];
  const float* W2 = (const float*)d_in[4];
  const float* b2 = (const float*)d_in[5];
  const float* Wl = (const float*)d_in[6];
  const float* bl = (const float*)d_in[7];
  float* out = (float*)d_out;

  const int* src = ei;
  const int* dst = ei + EE;

  char* ws = (char*)d_ws;
  size_t off = 0;
  auto alloc = [&](size_t bytes) {
    char* p = ws + off;
    off = (off + bytes + 255) & ~(size_t)255;
    return p;
  };
  float* dis = (float*)alloc((size_t)NN * 4);
  int* cnt = (int*)alloc((size_t)NN * 4);   // reused as `fill` during scatter
  int* offs = (int*)alloc((size_t)(NN + 1) * 4);
  int* scanb = (int*)alloc(1024 * 4);
  int* scanb2 = (int*)alloc(1024 * 4);
  int* csr = (int*)alloc((size_t)EE * 4);
  unsigned short* W1h = (unsigned short*)alloc((size_t)CC * CC * 2);
  unsigned short* W1l = (unsigned short*)alloc((size_t)CC * CC * 2);
  unsigned short* W2h = (unsigned short*)alloc((size_t)CC * CC * 2);
  unsigned short* W2l = (unsigned short*)alloc((size_t)CC * CC * 2);
  _Float16* hsbuf = (_Float16*)alloc((size_t)NN * CC * 2);  // GEMM out (fp16)
  float* h1 = (float*)alloc((size_t)NN * CC * 4);           // layer-1 activations

  hipMemsetAsync(cnt, 0, (size_t)NN * 4, stream);

  k_deg<<<2048, 256, 0, stream>>>(dst, cnt, EE);
  k_dis<<<(NN + 255) / 256, 256, 0, stream>>>(cnt, dis, NN);
  const int nb = (NN + 1023) / 1024;  // 98
  k_scan_local<<<nb, 1024, 0, stream>>>(cnt, offs, scanb, NN);
  k_scan_bsum<<<1, 128, 0, stream>>>(scanb, scanb2, nb);
  k_scan_add<<<(NN + 255) / 256, 256, 0, stream>>>(offs, scanb2, NN, nb);
  // cnt dead -> reuse as fill counters
  hipMemsetAsync(cnt, 0, (size_t)NN * 4, stream);
  k_scatter<<<2048, 256, 0, stream>>>(src, dst, offs, cnt, csr, EE);

  // weight prep (once per launch)
  k_wsplit<<<CC, CC, 0, stream>>>(W1, W1h, W1l);
  k_wsplit<<<CC, CC, 0, stream>>>(W2, W2h, W2l);

  dim3 ggrid((NN + 127) / 128, CC / 128);
  // layer 1: hs = (x @ W1) * dis[row] (fp16); h1 = relu(dis*(agg+self) + b1)
  k_gemm_mfma<<<ggrid, 256, 0, stream>>>(x, W1h, W1l, dis, hsbuf, NN);
  k_aggregate<<<(NN + 3) / 4, 256, 0, stream>>>(hsbuf, offs, csr, dis, b1, h1, NN);
  // layer 2 + fused readout
  k_gemm_mfma<<<ggrid, 256, 0, stream>>>(h1, W2h, W2l, dis, hsbuf, NN);
  k_aggregate_final<<<(NN + 3) / 4, 256, 0, stream>>>(hsbuf, offs, csr, dis, b2, Wl, bl, out, NN);
}

// Round 6
// 1056.752 us; speedup vs baseline: 1.9428x; 1.0470x over previous
//
#include <hip/hip_runtime.h>

#define NN 100000
#define CC 256
#define EE 3200000

typedef __attribute__((ext_vector_type(8))) short bf16x8;
typedef __attribute__((ext_vector_type(4))) float f32x4;
typedef __attribute__((ext_vector_type(4))) _Float16 f16x4;

__device__ __forceinline__ float4 f4add(float4 a, float4 b) {
  return make_float4(a.x + b.x, a.y + b.y, a.z + b.z, a.w + b.w);
}

__device__ __forceinline__ unsigned short f2bf(float f) {
  unsigned u = __float_as_uint(f);
  unsigned r = (u + 0x7fffu + ((u >> 16) & 1u)) >> 16;  // RTNE
  return (unsigned short)r;
}
__device__ __forceinline__ float bf2f(unsigned short h) {
  return __uint_as_float(((unsigned)h) << 16);
}

// ---- degree histogram ----
__global__ void k_deg(const int* __restrict__ dst, int* __restrict__ cnt, int n) {
  int i = blockIdx.x * blockDim.x + threadIdx.x;
  int stride = gridDim.x * blockDim.x;
  for (; i < n; i += stride) {
    unsigned d = (unsigned)dst[i];
    if (d < NN) atomicAdd(&cnt[d], 1);
  }
}

__global__ void k_dis(const int* __restrict__ cnt, float* __restrict__ dis, int n) {
  int i = blockIdx.x * blockDim.x + threadIdx.x;
  if (i < n) dis[i] = 1.0f / sqrtf((float)(cnt[i] + 1));
}

// ---- 3-phase parallel exclusive scan ----
__global__ void k_scan_local(const int* __restrict__ cnt, int* __restrict__ offs,
                             int* __restrict__ bsum, int n) {
  __shared__ int wsum[16];
  int t = threadIdx.x;
  int idx = blockIdx.x * 1024 + t;
  int lane = t & 63, wv = t >> 6;
  int v = (idx < n) ? cnt[idx] : 0;
  int x = v;
#pragma unroll
  for (int d = 1; d < 64; d <<= 1) {
    int y = __shfl_up(x, d, 64);
    if (lane >= d) x += y;
  }
  if (lane == 63) wsum[wv] = x;
  __syncthreads();
  int wpre = 0, total = 0;
#pragma unroll
  for (int w = 0; w < 16; ++w) {
    int s = wsum[w];
    if (w < wv) wpre += s;
    total += s;
  }
  if (idx < n) offs[idx] = wpre + x - v;
  if (t == 0) bsum[blockIdx.x] = total;
}

__global__ void k_scan_bsum(const int* __restrict__ bsum, int* __restrict__ bbase, int nb) {
  __shared__ int wsum[2];
  int t = threadIdx.x;  // 128 threads, nb <= 128
  int lane = t & 63, wv = t >> 6;
  int v = (t < nb) ? bsum[t] : 0;
  int x = v;
#pragma unroll
  for (int d = 1; d < 64; d <<= 1) {
    int y = __shfl_up(x, d, 64);
    if (lane >= d) x += y;
  }
  if (lane == 63) wsum[wv] = x;
  __syncthreads();
  int pre = (wv == 1) ? wsum[0] : 0;
  if (t < nb) bbase[t] = pre + x - v;
  if (t == nb - 1) bbase[nb] = pre + x;  // grand total
}

__global__ void k_scan_add(int* __restrict__ offs, const int* __restrict__ bbase,
                           int n, int nb) {
  int i = blockIdx.x * 256 + threadIdx.x;
  if (i < n) offs[i] += bbase[i >> 10];
  if (i == 0) offs[n] = bbase[nb];
}

// ---- scatter edge src indices into CSR slots ----
__global__ void k_scatter(const int* __restrict__ src, const int* __restrict__ dst,
                          const int* __restrict__ offs, int* __restrict__ fill,
                          int* __restrict__ csr, int n) {
  int i = blockIdx.x * blockDim.x + threadIdx.x;
  int stride = gridDim.x * blockDim.x;
  for (; i < n; i += stride) {
    unsigned d = (unsigned)dst[i];
    unsigned s = (unsigned)src[i];
    if (d < NN && s < NN) {
      int p = offs[d] + atomicAdd(&fill[d], 1);
      csr[p] = (int)s;
    }
  }
}

// ---- split W[k][n] (fp32) into transposed bf16 hi/lo: WT[n][k] ----
__global__ void k_wsplit(const float* __restrict__ W, unsigned short* __restrict__ WTh,
                         unsigned short* __restrict__ WTl) {
  int k = blockIdx.x, n = threadIdx.x;
  float w = W[k * CC + n];
  unsigned short h = f2bf(w);
  unsigned short l = f2bf(w - bf2f(h));
  WTh[n * CC + k] = h;
  WTl[n * CC + k] = l;
}

// ---- split-bf16 MFMA GEMM, full-N block: Out[m][0..256) (fp16) ----
// 512 threads, 8 waves (2 m x 4 n), M-tile 128, N = 256 (all), K-tile 32.
// A staged+converted exactly once (grid.y removed).
// A*W ~= Ah*Wh + Al*Wh + Ah*Wl  (lo*lo ~2^-18 rel, dropped)
#define LDA 40  // ushort row stride: 80 B, 16B-aligned, breaks pow2 bank stride

__global__ __launch_bounds__(512) void k_gemm_mfma(
    const float* __restrict__ A, const unsigned short* __restrict__ WTh,
    const unsigned short* __restrict__ WTl, const float* __restrict__ dis,
    _Float16* __restrict__ Out, int M) {
  __shared__ unsigned short Ah[128 * LDA], Al[128 * LDA];   // 10 KB each
  __shared__ unsigned short Bh[256 * LDA], Bl[256 * LDA];   // 20 KB each
  const int tid = threadIdx.x;
  const int wave = tid >> 6, lane = tid & 63;
  const int quad = lane >> 4, l16 = lane & 15;
  const int wm = wave >> 2, wn = wave & 3;  // 2x4 wave grid, 64x64 each
  const int row0 = blockIdx.x * 128;

  f32x4 acc[4][4];
#pragma unroll
  for (int i = 0; i < 4; ++i)
#pragma unroll
    for (int j = 0; j < 4; ++j) acc[i][j] = (f32x4){0.f, 0.f, 0.f, 0.f};

  for (int k0 = 0; k0 < CC; k0 += 32) {
    // stage A tile (128 x 32 fp32 -> bf16 hi/lo): 1024 float4s, 2/thread
#pragma unroll
    for (int q = 0; q < 2; ++q) {
      int idx = tid + 512 * q;
      int r = idx >> 3;
      int c4 = (idx & 7) << 2;
      int gr = row0 + r;
      float4 v = make_float4(0.f, 0.f, 0.f, 0.f);
      if (gr < M) v = *(const float4*)&A[(size_t)gr * CC + k0 + c4];
      ushort4 hv, lv;
      hv.x = f2bf(v.x); lv.x = f2bf(v.x - bf2f(hv.x));
      hv.y = f2bf(v.y); lv.y = f2bf(v.y - bf2f(hv.y));
      hv.z = f2bf(v.z); lv.z = f2bf(v.z - bf2f(hv.z));
      hv.w = f2bf(v.w); lv.w = f2bf(v.w - bf2f(hv.w));
      *(ushort4*)&Ah[r * LDA + c4] = hv;
      *(ushort4*)&Al[r * LDA + c4] = lv;
    }
    // stage B tile (256 n-rows x 32 k, bf16 transposed): 2048 ushort4s per buf
#pragma unroll
    for (int q = 0; q < 4; ++q) {
      int idx = tid + 512 * q;
      int r = idx >> 3;
      int c4 = (idx & 7) << 2;
      const size_t g = (size_t)r * CC + k0 + c4;
      *(ushort4*)&Bh[r * LDA + c4] = *(const ushort4*)&WTh[g];
      *(ushort4*)&Bl[r * LDA + c4] = *(const ushort4*)&WTl[g];
    }
    __syncthreads();

    bf16x8 bh[4], bl[4];
#pragma unroll
    for (int j = 0; j < 4; ++j) {
      int br = (wn * 64 + j * 16 + l16) * LDA + quad * 8;
      bh[j] = *(const bf16x8*)&Bh[br];
      bl[j] = *(const bf16x8*)&Bl[br];
    }
#pragma unroll
    for (int i = 0; i < 4; ++i) {
      int ar = (wm * 64 + i * 16 + l16) * LDA + quad * 8;
      bf16x8 ah = *(const bf16x8*)&Ah[ar];
      bf16x8 al = *(const bf16x8*)&Al[ar];
#pragma unroll
      for (int j = 0; j < 4; ++j) {
        acc[i][j] = __builtin_amdgcn_mfma_f32_16x16x32_bf16(ah, bh[j], acc[i][j], 0, 0, 0);
        acc[i][j] = __builtin_amdgcn_mfma_f32_16x16x32_bf16(al, bh[j], acc[i][j], 0, 0, 0);
        acc[i][j] = __builtin_amdgcn_mfma_f32_16x16x32_bf16(ah, bl[j], acc[i][j], 0, 0, 0);
      }
    }
    __syncthreads();
  }

  // epilogue: D layout col=lane&15, row=quad*4+reg (m89-verified); fp16 store
#pragma unroll
  for (int i = 0; i < 4; ++i) {
#pragma unroll
    for (int r4 = 0; r4 < 4; ++r4) {
      int r = row0 + wm * 64 + i * 16 + quad * 4 + r4;
      if (r < M) {
        float sc = dis[r];
#pragma unroll
        for (int j = 0; j < 4; ++j) {
          Out[(size_t)r * CC + wn * 64 + j * 16 + l16] =
              (_Float16)(acc[i][j][r4] * sc);
        }
      }
    }
  }
}

// ---- CSR aggregation (fp16 gather): h1[i] = relu(dis[i]*(sum hs[src] + hs[i]) + b) ----
__global__ __launch_bounds__(256) void k_aggregate(
    const _Float16* __restrict__ hs, const int* __restrict__ offs,
    const int* __restrict__ csr, const float* __restrict__ dis,
    const float* __restrict__ bias, float* __restrict__ out, int n) {
  int node = blockIdx.x * 4 + (threadIdx.x >> 6);
  if (node >= n) return;
  int lane = threadIdx.x & 63;
  int c4 = lane << 2;
  int beg = offs[node], end = offs[node + 1];
  f16x4 sv = *(const f16x4*)&hs[(size_t)node * CC + c4];  // self-loop term
  float4 a0 = make_float4((float)sv.x, (float)sv.y, (float)sv.z, (float)sv.w);
  float4 a1 = make_float4(0.f, 0.f, 0.f, 0.f);
  float4 a2 = make_float4(0.f, 0.f, 0.f, 0.f);
  float4 a3 = make_float4(0.f, 0.f, 0.f, 0.f);
  int e = beg;
  for (; e + 4 <= end; e += 4) {
    int s0 = csr[e], s1 = csr[e + 1], s2 = csr[e + 2], s3 = csr[e + 3];
    f16x4 v0 = *(const f16x4*)&hs[(size_t)s0 * CC + c4];
    f16x4 v1 = *(const f16x4*)&hs[(size_t)s1 * CC + c4];
    f16x4 v2 = *(const f16x4*)&hs[(size_t)s2 * CC + c4];
    f16x4 v3 = *(const f16x4*)&hs[(size_t)s3 * CC + c4];
    a0.x += (float)v0.x; a0.y += (float)v0.y; a0.z += (float)v0.z; a0.w += (float)v0.w;
    a1.x += (float)v1.x; a1.y += (float)v1.y; a1.z += (float)v1.z; a1.w += (float)v1.w;
    a2.x += (float)v2.x; a2.y += (float)v2.y; a2.z += (float)v2.z; a2.w += (float)v2.w;
    a3.x += (float)v3.x; a3.y += (float)v3.y; a3.z += (float)v3.z; a3.w += (float)v3.w;
  }
  for (; e < end; ++e) {
    int s0 = csr[e];
    f16x4 v0 = *(const f16x4*)&hs[(size_t)s0 * CC + c4];
    a0.x += (float)v0.x; a0.y += (float)v0.y; a0.z += (float)v0.z; a0.w += (float)v0.w;
  }
  float4 acc = f4add(f4add(a0, a1), f4add(a2, a3));
  float sc = dis[node];
  float4 bv = *(const float4*)&bias[c4];
  float4 r;
  r.x = fmaxf(acc.x * sc + bv.x, 0.f);
  r.y = fmaxf(acc.y * sc + bv.y, 0.f);
  r.z = fmaxf(acc.z * sc + bv.z, 0.f);
  r.w = fmaxf(acc.w * sc + bv.w, 0.f);
  *(float4*)&out[(size_t)node * CC + c4] = r;
}

// ---- fused layer-2 aggregate + readout: out[i] = relu(...) . Wl + bl ----
__global__ __launch_bounds__(256) void k_aggregate_final(
    const _Float16* __restrict__ hs, const int* __restrict__ offs,
    const int* __restrict__ csr, const float* __restrict__ dis,
    const float* __restrict__ bias, const float* __restrict__ Wl,
    const float* __restrict__ bl, float* __restrict__ out, int n) {
  int node = blockIdx.x * 4 + (threadIdx.x >> 6);
  if (node >= n) return;
  int lane = threadIdx.x & 63;
  int c4 = lane << 2;
  int beg = offs[node], end = offs[node + 1];
  f16x4 sv = *(const f16x4*)&hs[(size_t)node * CC + c4];
  float4 a0 = make_float4((float)sv.x, (float)sv.y, (float)sv.z, (float)sv.w);
  float4 a1 = make_float4(0.f, 0.f, 0.f, 0.f);
  float4 a2 = make_float4(0.f, 0.f, 0.f, 0.f);
  float4 a3 = make_float4(0.f, 0.f, 0.f, 0.f);
  int e = beg;
  for (; e + 4 <= end; e += 4) {
    int s0 = csr[e], s1 = csr[e + 1], s2 = csr[e + 2], s3 = csr[e + 3];
    f16x4 v0 = *(const f16x4*)&hs[(size_t)s0 * CC + c4];
    f16x4 v1 = *(const f16x4*)&hs[(size_t)s1 * CC + c4];
    f16x4 v2 = *(const f16x4*)&hs[(size_t)s2 * CC + c4];
    f16x4 v3 = *(const f16x4*)&hs[(size_t)s3 * CC + c4];
    a0.x += (float)v0.x; a0.y += (float)v0.y; a0.z += (float)v0.z; a0.w += (float)v0.w;
    a1.x += (float)v1.x; a1.y += (float)v1.y; a1.z += (float)v1.z; a1.w += (float)v1.w;
    a2.x += (float)v2.x; a2.y += (float)v2.y; a2.z += (float)v2.z; a2.w += (float)v2.w;
    a3.x += (float)v3.x; a3.y += (float)v3.y; a3.z += (float)v3.z; a3.w += (float)v3.w;
  }
  for (; e < end; ++e) {
    int s0 = csr[e];
    f16x4 v0 = *(const f16x4*)&hs[(size_t)s0 * CC + c4];
    a0.x += (float)v0.x; a0.y += (float)v0.y; a0.z += (float)v0.z; a0.w += (float)v0.w;
  }
  float4 acc = f4add(f4add(a0, a1), f4add(a2, a3));
  float sc = dis[node];
  float4 bv = *(const float4*)&bias[c4];
  float4 w = *(const float4*)&Wl[c4];
  float s = fmaxf(acc.x * sc + bv.x, 0.f) * w.x +
            fmaxf(acc.y * sc + bv.y, 0.f) * w.y +
            fmaxf(acc.z * sc + bv.z, 0.f) * w.z +
            fmaxf(acc.w * sc + bv.w, 0.f) * w.w;
#pragma unroll
  for (int d = 32; d > 0; d >>= 1) s += __shfl_down(s, d, 64);
  if (lane == 0) out[node] = s + bl[0];
}

extern "C" void kernel_launch(void* const* d_in, const int* in_sizes, int n_in,
                              void* d_out, int out_size, void* d_ws, size_t ws_size,
                              hipStream_t stream) {
  const float* x = (const float*)d_in[0];
  const int* ei = (const int*)d_in[1];  // int64 in reference -> int32 on device
  const float* W1 = (const float*)d_in[2];
  const float* b1 = (const float*)d_in[3];
  const float* W2 = (const float*)d_in[4];
  const float* b2 = (const float*)d_in[5];
  const float* Wl = (const float*)d_in[6];
  const float* bl = (const float*)d_in[7];
  float* out = (float*)d_out;

  const int* src = ei;
  const int* dst = ei + EE;

  char* ws = (char*)d_ws;
  size_t off = 0;
  auto alloc = [&](size_t bytes) {
    char* p = ws + off;
    off = (off + bytes + 255) & ~(size_t)255;
    return p;
  };
  float* dis = (float*)alloc((size_t)NN * 4);
  int* cnt = (int*)alloc((size_t)NN * 4);   // reused as `fill` during scatter
  int* offs = (int*)alloc((size_t)(NN + 1) * 4);
  int* scanb = (int*)alloc(1024 * 4);
  int* scanb2 = (int*)alloc(1024 * 4);
  int* csr = (int*)alloc((size_t)EE * 4);
  unsigned short* W1h = (unsigned short*)alloc((size_t)CC * CC * 2);
  unsigned short* W1l = (unsigned short*)alloc((size_t)CC * CC * 2);
  unsigned short* W2h = (unsigned short*)alloc((size_t)CC * CC * 2);
  unsigned short* W2l = (unsigned short*)alloc((size_t)CC * CC * 2);
  _Float16* hsbuf = (_Float16*)alloc((size_t)NN * CC * 2);  // GEMM out (fp16)
  float* h1 = (float*)alloc((size_t)NN * CC * 4);           // layer-1 activations

  hipMemsetAsync(cnt, 0, (size_t)NN * 4, stream);

  k_deg<<<2048, 256, 0, stream>>>(dst, cnt, EE);
  k_dis<<<(NN + 255) / 256, 256, 0, stream>>>(cnt, dis, NN);
  const int nb = (NN + 1023) / 1024;  // 98
  k_scan_local<<<nb, 1024, 0, stream>>>(cnt, offs, scanb, NN);
  k_scan_bsum<<<1, 128, 0, stream>>>(scanb, scanb2, nb);
  k_scan_add<<<(NN + 255) / 256, 256, 0, stream>>>(offs, scanb2, NN, nb);
  // cnt dead -> reuse as fill counters
  hipMemsetAsync(cnt, 0, (size_t)NN * 4, stream);
  k_scatter<<<2048, 256, 0, stream>>>(src, dst, offs, cnt, csr, EE);

  // weight prep (once per launch)
  k_wsplit<<<CC, CC, 0, stream>>>(W1, W1h, W1l);
  k_wsplit<<<CC, CC, 0, stream>>>(W2, W2h, W2l);

  const int gblocks = (NN + 127) / 128;
  // layer 1: hs = (x @ W1) * dis[row] (fp16); h1 = relu(dis*(agg+self) + b1)
  k_gemm_mfma<<<gblocks, 512, 0, stream>>>(x, W1h, W1l, dis, hsbuf, NN);
  k_aggregate<<<(NN + 3) / 4, 256, 0, stream>>>(hsbuf, offs, csr, dis, b1, h1, NN);
  // layer 2 + fused readout
  k_gemm_mfma<<<gblocks, 512, 0, stream>>>(h1, W2h, W2l, dis, hsbuf, NN);
  k_aggregate_final<<<(NN + 3) / 4, 256, 0, stream>>>(hsbuf, offs, csr, dis, b2, Wl, bl, out, NN);
}